// Round 11
// baseline (163.143 us; speedup 1.0000x reference)
//
#include <hip/hip_runtime.h>
#include <hip/hip_bf16.h>

#define BSZ 4
#define NN 512
#define INDIM 256
#define H1 128
#define EMBD 64

#define PRED_OFF  (BSZ*NN*NN)                   // 1048576 elements
#define PRED_PER_B (NN*(NN-1)*2)                // 523264
#define EMB_OFF   (PRED_OFF + BSZ*PRED_PER_B)   // 3141632

typedef __attribute__((ext_vector_type(8))) short bf16x8;
typedef __attribute__((ext_vector_type(4))) float f32x4;

static __device__ __forceinline__ short bfs(float x) {
  return (short)__builtin_bit_cast(unsigned short, __float2bfloat16(x));
}
static __device__ __forceinline__ bf16x8 pack8(float4 a, float4 b) {
  bf16x8 r;
  r[0] = bfs(a.x); r[1] = bfs(a.y); r[2] = bfs(a.z); r[3] = bfs(a.w);
  r[4] = bfs(b.x); r[5] = bfs(b.y); r[6] = bfs(b.z); r[7] = bfs(b.w);
  return r;
}

// Kernel 1: node MLP -> emb (f32 into d_out) + optional bf16 mirror in ws.
template<bool WS>
__global__ __launch_bounds__(256) void k1_embed(
    const float* __restrict__ nf, const float* __restrict__ fc1w,
    const float* __restrict__ fc1b, const float* __restrict__ fc2w,
    const float* __restrict__ fc2b, float* __restrict__ out,
    unsigned short* __restrict__ ebf)
{
  __shared__ float nfs[4][INDIM];
  __shared__ float hs[4][H1];
  const int t = threadIdx.x;
  const int nb = blockIdx.x * 4;

  {
    const int nd = t >> 6, off = (t & 63) * 4;
    *reinterpret_cast<float4*>(&nfs[nd][off]) =
        *reinterpret_cast<const float4*>(nf + (size_t)(nb + nd) * INDIM + off);
  }
  __syncthreads();
  {
    const int c = t & 127, grp = t >> 7;
    float a0 = 0.f, a1 = 0.f;
    for (int f = 0; f < INDIM; ++f) {
      const float w = fc1w[f * H1 + c];
      a0 = fmaf(nfs[grp][f], w, a0);
      a1 = fmaf(nfs[grp + 2][f], w, a1);
    }
    const float bb = fc1b[c];
    a0 += bb; a1 += bb;
    hs[grp][c]     = a0 > 0.f ? a0 : 0.01f * a0;
    hs[grp + 2][c] = a1 > 0.f ? a1 : 0.01f * a1;
  }
  __syncthreads();
  {
    const int d = t & 63, nd = t >> 6;
    float acc = 0.f;
    for (int f = 0; f < H1; ++f) acc = fmaf(hs[nd][f], fc2w[f * EMBD + d], acc);
    acc += fc2b[d];
    const float e = acc > 0.f ? acc : 0.01f * acc;
    const size_t idx = (size_t)(nb + nd) * EMBD + d;
    out[EMB_OFF + idx] = e;
    if (WS) ebf[idx] = (unsigned short)bfs(e);
  }
}

// Kernel 2: ONE WAVE per block. Block owns (b, i, j-half of 256 j).
template<bool WS>
__global__ __launch_bounds__(64, 4) void k2_edges(
    const float* __restrict__ e1w, const float* __restrict__ e1b,
    const float* __restrict__ e2w, const float* __restrict__ e2b,
    float* __restrict__ out, const unsigned short* __restrict__ ebf)
{
  __shared__ float embi[64];
  __shared__ float ash[64];   // a_i[h] + e1_b[h]
  __shared__ float wds[64];   // e2w[h][1] - e2w[h][0]
  const int t = threadIdx.x;            // lane 0..63
  const int blk = blockIdx.x;
  const int b = blk >> 10;              // 1024 blocks per batch
  const int rr = blk & 1023;
  const int i = rr >> 1;
  const int jh = rr & 1;                // j-half: [jh*256, jh*256+256)
  const float* __restrict__ Ef = out + EMB_OFF;

  embi[t] = Ef[((size_t)(b * NN) + i) * EMBD + t];
  wds[t]  = e2w[2 * t + 1] - e2w[2 * t];
  __syncthreads();

  {
    float acc = 0.f;
#pragma unroll 8
    for (int dd = 0; dd < EMBD; ++dd)
      acc = fmaf(embi[dd], e1w[dd * 64 + t], acc);
    ash[t] = acc + e1b[t];
  }
  __syncthreads();

  const int lg = t >> 4, ll = t & 15;

  f32x4 ci[4], wd4[4];
#pragma unroll
  for (int mt = 0; mt < 4; ++mt) {
    ci[mt]  = *reinterpret_cast<const f32x4*>(&ash[mt * 16 + lg * 4]);
    wd4[mt] = *reinterpret_cast<const f32x4*>(&wds[mt * 16 + lg * 4]);
  }
  const float ldbias = e2b[1] - e2b[0];

  bf16x8 afr[4][2];
#pragma unroll
  for (int ks = 0; ks < 2; ++ks) {
    float e8[8];
    *reinterpret_cast<float4*>(&e8[0]) =
        *reinterpret_cast<const float4*>(&embi[ks * 32 + lg * 8]);
    *reinterpret_cast<float4*>(&e8[4]) =
        *reinterpret_cast<const float4*>(&embi[ks * 32 + lg * 8 + 4]);
#pragma unroll
    for (int mt = 0; mt < 4; ++mt) {
      const int h = mt * 16 + ll;
      bf16x8 a;
#pragma unroll
      for (int q = 0; q < 8; ++q) {
        const int d = ks * 32 + lg * 8 + q;
        a[q] = bfs(fmaf(e8[q], e1w[(64 + d) * 64 + h], -e1w[d * 64 + h]));
      }
      afr[mt][ks] = a;
    }
  }

  const size_t adj_base = ((size_t)(b * NN) + i) * NN;
  const size_t pred_base =
      (size_t)PRED_OFF + (size_t)b * PRED_PER_B + (size_t)i * (NN - 1) * 2;

  auto loadB = [&](int j0, bf16x8& o0, bf16x8& o1) {
    if (WS) {
      const unsigned short* p =
          ebf + ((size_t)(b * NN) + j0 + ll) * EMBD + lg * 8;
      o0 = *reinterpret_cast<const bf16x8*>(p);
      o1 = *reinterpret_cast<const bf16x8*>(p + 32);
    } else {
      const float* ef = Ef + ((size_t)(b * NN) + j0 + ll) * EMBD + lg * 8;
      const float4 fa = *reinterpret_cast<const float4*>(ef);
      const float4 fb = *reinterpret_cast<const float4*>(ef + 4);
      const float4 fc = *reinterpret_cast<const float4*>(ef + 32);
      const float4 fd = *reinterpret_cast<const float4*>(ef + 36);
      o0 = pack8(fa, fb);
      o1 = pack8(fc, fd);
    }
  };

  const int jbase = jh * 256;
  bf16x8 pb0, pb1;
  loadB(jbase, pb0, pb1);

#pragma unroll 2
  for (int nt = 0; nt < 16; ++nt) {
    const bf16x8 b0 = pb0, b1 = pb1;
    if (nt < 15) loadB(jbase + (nt + 1) * 16, pb0, pb1);

    f32x4 acc[4];
#pragma unroll
    for (int mt = 0; mt < 4; ++mt)
      acc[mt] = __builtin_amdgcn_mfma_f32_16x16x32_bf16(afr[mt][0], b0, ci[mt], 0, 0, 0);
#pragma unroll
    for (int mt = 0; mt < 4; ++mt)
      acc[mt] = __builtin_amdgcn_mfma_f32_16x16x32_bf16(afr[mt][1], b1, acc[mt], 0, 0, 0);

    float lp0 = 0.f, lp1 = 0.f, lp2 = 0.f, lp3 = 0.f;
#pragma unroll
    for (int mt = 0; mt < 4; ++mt) {
      lp0 = fmaf(fmaxf(acc[mt][0], 0.f), wd4[mt][0], lp0);
      lp1 = fmaf(fmaxf(acc[mt][1], 0.f), wd4[mt][1], lp1);
      lp2 = fmaf(fmaxf(acc[mt][2], 0.f), wd4[mt][2], lp2);
      lp3 = fmaf(fmaxf(acc[mt][3], 0.f), wd4[mt][3], lp3);
    }
    float ldp = (lp0 + lp1) + (lp2 + lp3);
    ldp += __shfl_xor(ldp, 16, 64);
    ldp += __shfl_xor(ldp, 32, 64);

    const float x = ldp + ldbias;
    const float e = __builtin_amdgcn_exp2f(x * -1.44269504f);
    const float p1 = __builtin_amdgcn_rcpf(1.f + e);
    const float p0 = e * p1;

    if (t < 32) {
      const int j = jbase + nt * 16 + ll;
      if (t < 16) {
        out[adj_base + j] = p1;
      } else if (j != i) {
        const int jj = j - (j > i ? 1 : 0);
        *reinterpret_cast<float2*>(out + pred_base + (size_t)jj * 2) =
            make_float2(p0, p1);
      }
    }
  }
}

extern "C" void kernel_launch(void* const* d_in, const int* in_sizes, int n_in,
                              void* d_out, int out_size, void* d_ws, size_t ws_size,
                              hipStream_t stream) {
  const float* nf   = (const float*)d_in[0];
  const float* fc1w = (const float*)d_in[1];
  const float* fc1b = (const float*)d_in[2];
  const float* fc2w = (const float*)d_in[3];
  const float* fc2b = (const float*)d_in[4];
  const float* e1w  = (const float*)d_in[5];
  const float* e1b  = (const float*)d_in[6];
  const float* e2w  = (const float*)d_in[7];
  const float* e2b  = (const float*)d_in[8];
  float* out = (float*)d_out;
  unsigned short* ebf = (unsigned short*)d_ws;
  const bool use_ws = ws_size >= (size_t)BSZ * NN * EMBD * sizeof(unsigned short);

  // DIFFERENTIAL MEASUREMENT ROUND: k2 launched 3x (idempotent — identical
  // outputs each time; same work every call, graph-capture safe).
  // dur = floor + k1 + k2_cold + 2*k2_warm  ->  resolves k2 vs harness floor.
  if (use_ws) {
    k1_embed<true><<<BSZ * NN / 4, 256, 0, stream>>>(nf, fc1w, fc1b, fc2w, fc2b, out, ebf);
    k2_edges<true><<<BSZ * NN * 2, 64, 0, stream>>>(e1w, e1b, e2w, e2b, out, ebf);
    k2_edges<true><<<BSZ * NN * 2, 64, 0, stream>>>(e1w, e1b, e2w, e2b, out, ebf);
    k2_edges<true><<<BSZ * NN * 2, 64, 0, stream>>>(e1w, e1b, e2w, e2b, out, ebf);
  } else {
    k1_embed<false><<<BSZ * NN / 4, 256, 0, stream>>>(nf, fc1w, fc1b, fc2w, fc2b, out, nullptr);
    k2_edges<false><<<BSZ * NN * 2, 64, 0, stream>>>(e1w, e1b, e2w, e2b, out, nullptr);
    k2_edges<false><<<BSZ * NN * 2, 64, 0, stream>>>(e1w, e1b, e2w, e2b, out, nullptr);
    k2_edges<false><<<BSZ * NN * 2, 64, 0, stream>>>(e1w, e1b, e2w, e2b, out, nullptr);
  }
}

// Round 12
// 111.677 us; speedup vs baseline: 1.4608x; 1.4608x over previous
//
#include <hip/hip_runtime.h>
#include <hip/hip_bf16.h>

#define BSZ 4
#define NN 512
#define INDIM 256
#define H1 128
#define EMBD 64

#define PRED_OFF  (BSZ*NN*NN)                   // 1048576 elements
#define PRED_PER_B (NN*(NN-1)*2)                // 523264
#define EMB_OFF   (PRED_OFF + BSZ*PRED_PER_B)   // 3141632

typedef __attribute__((ext_vector_type(8))) short bf16x8;
typedef __attribute__((ext_vector_type(4))) float f32x4;

static __device__ __forceinline__ short bfs(float x) {
  return (short)__builtin_bit_cast(unsigned short, __float2bfloat16(x));
}
static __device__ __forceinline__ bf16x8 pack8(float4 a, float4 b) {
  bf16x8 r;
  r[0] = bfs(a.x); r[1] = bfs(a.y); r[2] = bfs(a.z); r[3] = bfs(a.w);
  r[4] = bfs(b.x); r[5] = bfs(b.y); r[6] = bfs(b.z); r[7] = bfs(b.w);
  return r;
}

// Kernel 1: node MLP -> emb (f32 into d_out) + optional bf16 mirror in ws.
template<bool WS>
__global__ __launch_bounds__(256) void k1_embed(
    const float* __restrict__ nf, const float* __restrict__ fc1w,
    const float* __restrict__ fc1b, const float* __restrict__ fc2w,
    const float* __restrict__ fc2b, float* __restrict__ out,
    unsigned short* __restrict__ ebf)
{
  __shared__ float nfs[4][INDIM];
  __shared__ float hs[4][H1];
  const int t = threadIdx.x;
  const int nb = blockIdx.x * 4;

  {
    const int nd = t >> 6, off = (t & 63) * 4;
    *reinterpret_cast<float4*>(&nfs[nd][off]) =
        *reinterpret_cast<const float4*>(nf + (size_t)(nb + nd) * INDIM + off);
  }
  __syncthreads();
  {
    const int c = t & 127, grp = t >> 7;
    float a0 = 0.f, a1 = 0.f;
    for (int f = 0; f < INDIM; ++f) {
      const float w = fc1w[f * H1 + c];
      a0 = fmaf(nfs[grp][f], w, a0);
      a1 = fmaf(nfs[grp + 2][f], w, a1);
    }
    const float bb = fc1b[c];
    a0 += bb; a1 += bb;
    hs[grp][c]     = a0 > 0.f ? a0 : 0.01f * a0;
    hs[grp + 2][c] = a1 > 0.f ? a1 : 0.01f * a1;
  }
  __syncthreads();
  {
    const int d = t & 63, nd = t >> 6;
    float acc = 0.f;
    for (int f = 0; f < H1; ++f) acc = fmaf(hs[nd][f], fc2w[f * EMBD + d], acc);
    acc += fc2b[d];
    const float e = acc > 0.f ? acc : 0.01f * acc;
    const size_t idx = (size_t)(nb + nd) * EMBD + d;
    out[EMB_OFF + idx] = e;
    if (WS) ebf[idx] = (unsigned short)bfs(e);
  }
}

// Kernel 2: ONE WAVE per block. Block owns (b, i, j-half of 256 j).
// Inner loop writes per-lane-group partial logits to LDS; a deferred
// wave-parallel epilogue does the sigmoid + coalesced stores.
template<bool WS>
__global__ __launch_bounds__(64, 4) void k2_edges(
    const float* __restrict__ e1w, const float* __restrict__ e1b,
    const float* __restrict__ e2w, const float* __restrict__ e2b,
    float* __restrict__ out, const unsigned short* __restrict__ ebf)
{
  __shared__ float embi[64];
  __shared__ float ash[64];             // a_i[h] + e1_b[h]
  __shared__ float wds[64];             // e2w[h][1] - e2w[h][0]
  __shared__ __align__(16) float part[256][4];  // per-j partial logits
  const int t = threadIdx.x;            // lane 0..63
  const int blk = blockIdx.x;
  const int b = blk >> 10;              // 1024 blocks per batch
  const int rr = blk & 1023;
  const int i = rr >> 1;
  const int jh = rr & 1;                // j-half: [jh*256, jh*256+256)
  const float* __restrict__ Ef = out + EMB_OFF;

  embi[t] = Ef[((size_t)(b * NN) + i) * EMBD + t];
  wds[t]  = e2w[2 * t + 1] - e2w[2 * t];
  __syncthreads();

  {
    float acc = 0.f;
#pragma unroll 8
    for (int dd = 0; dd < EMBD; ++dd)
      acc = fmaf(embi[dd], e1w[dd * 64 + t], acc);
    ash[t] = acc + e1b[t];
  }
  __syncthreads();

  const int lg = t >> 4, ll = t & 15;

  f32x4 ci[4], wd4[4];
#pragma unroll
  for (int mt = 0; mt < 4; ++mt) {
    ci[mt]  = *reinterpret_cast<const f32x4*>(&ash[mt * 16 + lg * 4]);
    wd4[mt] = *reinterpret_cast<const f32x4*>(&wds[mt * 16 + lg * 4]);
  }

  // A fragments built directly in registers:
  // afr[mt][ks][q] = B'[d = ks*32+lg*8+q][h = mt*16+ll]
  bf16x8 afr[4][2];
#pragma unroll
  for (int ks = 0; ks < 2; ++ks) {
    float e8[8];
    *reinterpret_cast<float4*>(&e8[0]) =
        *reinterpret_cast<const float4*>(&embi[ks * 32 + lg * 8]);
    *reinterpret_cast<float4*>(&e8[4]) =
        *reinterpret_cast<const float4*>(&embi[ks * 32 + lg * 8 + 4]);
#pragma unroll
    for (int mt = 0; mt < 4; ++mt) {
      const int h = mt * 16 + ll;
      bf16x8 a;
#pragma unroll
      for (int q = 0; q < 8; ++q) {
        const int d = ks * 32 + lg * 8 + q;
        a[q] = bfs(fmaf(e8[q], e1w[(64 + d) * 64 + h], -e1w[d * 64 + h]));
      }
      afr[mt][ks] = a;
    }
  }

  auto loadB = [&](int j0, bf16x8& o0, bf16x8& o1) {
    if (WS) {
      const unsigned short* p =
          ebf + ((size_t)(b * NN) + j0 + ll) * EMBD + lg * 8;
      o0 = *reinterpret_cast<const bf16x8*>(p);
      o1 = *reinterpret_cast<const bf16x8*>(p + 32);
    } else {
      const float* ef = Ef + ((size_t)(b * NN) + j0 + ll) * EMBD + lg * 8;
      const float4 fa = *reinterpret_cast<const float4*>(ef);
      const float4 fb = *reinterpret_cast<const float4*>(ef + 4);
      const float4 fc = *reinterpret_cast<const float4*>(ef + 32);
      const float4 fd = *reinterpret_cast<const float4*>(ef + 36);
      o0 = pack8(fa, fb);
      o1 = pack8(fc, fd);
    }
  };

  const int jbase = jh * 256;
  bf16x8 pb0, pb1;
  loadB(jbase, pb0, pb1);

#pragma unroll 2
  for (int nt = 0; nt < 16; ++nt) {
    const bf16x8 b0 = pb0, b1 = pb1;
    if (nt < 15) loadB(jbase + (nt + 1) * 16, pb0, pb1);

    f32x4 acc[4];
#pragma unroll
    for (int mt = 0; mt < 4; ++mt)
      acc[mt] = __builtin_amdgcn_mfma_f32_16x16x32_bf16(afr[mt][0], b0, ci[mt], 0, 0, 0);
#pragma unroll
    for (int mt = 0; mt < 4; ++mt)
      acc[mt] = __builtin_amdgcn_mfma_f32_16x16x32_bf16(afr[mt][1], b1, acc[mt], 0, 0, 0);

    float lp0 = 0.f, lp1 = 0.f, lp2 = 0.f, lp3 = 0.f;
#pragma unroll
    for (int mt = 0; mt < 4; ++mt) {
      lp0 = fmaf(fmaxf(acc[mt][0], 0.f), wd4[mt][0], lp0);
      lp1 = fmaf(fmaxf(acc[mt][1], 0.f), wd4[mt][1], lp1);
      lp2 = fmaf(fmaxf(acc[mt][2], 0.f), wd4[mt][2], lp2);
      lp3 = fmaf(fmaxf(acc[mt][3], 0.f), wd4[mt][3], lp3);
    }
    // per-lane-group partial (includes this lg's ci share); defer the rest
    part[nt * 16 + ll][lg] = (lp0 + lp1) + (lp2 + lp3);
  }
  __syncthreads();

  // Deferred epilogue: each lane finishes 4 j's (sigmoid + coalesced stores)
  const float ldbias = e2b[1] - e2b[0];
  const size_t adj_base = ((size_t)(b * NN) + i) * NN + jbase;
  const size_t pred_base =
      (size_t)PRED_OFF + (size_t)b * PRED_PER_B + (size_t)i * (NN - 1) * 2;

#pragma unroll
  for (int e4 = 0; e4 < 4; ++e4) {
    const int jl = e4 * 64 + t;
    const f32x4 p4 = *reinterpret_cast<const f32x4*>(&part[jl][0]);
    const float x = (p4[0] + p4[1]) + (p4[2] + p4[3]) + ldbias;
    const float e = __builtin_amdgcn_exp2f(x * -1.44269504f);
    const float p1 = __builtin_amdgcn_rcpf(1.f + e);
    const float p0 = e * p1;

    const int j = jbase + jl;
    out[adj_base + jl] = p1;
    if (j != i) {
      const int jj = j - (j > i ? 1 : 0);
      *reinterpret_cast<float2*>(out + pred_base + (size_t)jj * 2) =
          make_float2(p0, p1);
    }
  }
}

extern "C" void kernel_launch(void* const* d_in, const int* in_sizes, int n_in,
                              void* d_out, int out_size, void* d_ws, size_t ws_size,
                              hipStream_t stream) {
  const float* nf   = (const float*)d_in[0];
  const float* fc1w = (const float*)d_in[1];
  const float* fc1b = (const float*)d_in[2];
  const float* fc2w = (const float*)d_in[3];
  const float* fc2b = (const float*)d_in[4];
  const float* e1w  = (const float*)d_in[5];
  const float* e1b  = (const float*)d_in[6];
  const float* e2w  = (const float*)d_in[7];
  const float* e2b  = (const float*)d_in[8];
  float* out = (float*)d_out;
  unsigned short* ebf = (unsigned short*)d_ws;
  const bool use_ws = ws_size >= (size_t)BSZ * NN * EMBD * sizeof(unsigned short);

  if (use_ws) {
    k1_embed<true><<<BSZ * NN / 4, 256, 0, stream>>>(nf, fc1w, fc1b, fc2w, fc2b, out, ebf);
    k2_edges<true><<<BSZ * NN * 2, 64, 0, stream>>>(e1w, e1b, e2w, e2b, out, ebf);
  } else {
    k1_embed<false><<<BSZ * NN / 4, 256, 0, stream>>>(nf, fc1w, fc1b, fc2w, fc2b, out, nullptr);
    k2_edges<false><<<BSZ * NN * 2, 64, 0, stream>>>(e1w, e1b, e2w, e2b, out, nullptr);
  }
}

// Round 13
// 109.855 us; speedup vs baseline: 1.4851x; 1.0166x over previous
//
#include <hip/hip_runtime.h>
#include <hip/hip_bf16.h>

#define BSZ 4
#define NN 512
#define INDIM 256
#define H1 128
#define EMBD 64

#define PRED_OFF  (BSZ*NN*NN)                   // 1048576 elements
#define PRED_PER_B (NN*(NN-1)*2)                // 523264
#define EMB_OFF   (PRED_OFF + BSZ*PRED_PER_B)   // 3141632

typedef __attribute__((ext_vector_type(8))) short bf16x8;
typedef __attribute__((ext_vector_type(4))) float f32x4;

static __device__ __forceinline__ short bfs(float x) {
  return (short)__builtin_bit_cast(unsigned short, __float2bfloat16(x));
}
static __device__ __forceinline__ bf16x8 pack8(float4 a, float4 b) {
  bf16x8 r;
  r[0] = bfs(a.x); r[1] = bfs(a.y); r[2] = bfs(a.z); r[3] = bfs(a.w);
  r[4] = bfs(b.x); r[5] = bfs(b.y); r[6] = bfs(b.z); r[7] = bfs(b.w);
  return r;
}

// Kernel 1: node MLP -> emb (f32 into d_out) + optional bf16 mirror in ws.
template<bool WS>
__global__ __launch_bounds__(256) void k1_embed(
    const float* __restrict__ nf, const float* __restrict__ fc1w,
    const float* __restrict__ fc1b, const float* __restrict__ fc2w,
    const float* __restrict__ fc2b, float* __restrict__ out,
    unsigned short* __restrict__ ebf)
{
  __shared__ float nfs[4][INDIM];
  __shared__ float hs[4][H1];
  const int t = threadIdx.x;
  const int nb = blockIdx.x * 4;

  {
    const int nd = t >> 6, off = (t & 63) * 4;
    *reinterpret_cast<float4*>(&nfs[nd][off]) =
        *reinterpret_cast<const float4*>(nf + (size_t)(nb + nd) * INDIM + off);
  }
  __syncthreads();
  {
    const int c = t & 127, grp = t >> 7;
    float a0 = 0.f, a1 = 0.f;
    for (int f = 0; f < INDIM; ++f) {
      const float w = fc1w[f * H1 + c];
      a0 = fmaf(nfs[grp][f], w, a0);
      a1 = fmaf(nfs[grp + 2][f], w, a1);
    }
    const float bb = fc1b[c];
    a0 += bb; a1 += bb;
    hs[grp][c]     = a0 > 0.f ? a0 : 0.01f * a0;
    hs[grp + 2][c] = a1 > 0.f ? a1 : 0.01f * a1;
  }
  __syncthreads();
  {
    const int d = t & 63, nd = t >> 6;
    float acc = 0.f;
    for (int f = 0; f < H1; ++f) acc = fmaf(hs[nd][f], fc2w[f * EMBD + d], acc);
    acc += fc2b[d];
    const float e = acc > 0.f ? acc : 0.01f * acc;
    const size_t idx = (size_t)(nb + nd) * EMBD + d;
    out[EMB_OFF + idx] = e;
    if (WS) ebf[idx] = (unsigned short)bfs(e);
  }
}

// Kernel 2: ONE WAVE per block. Block owns (b, i, j-half of 256 j).
// Depth-2 software prefetch (two register tile-pairs in rotation);
// deferred wave-parallel epilogue for sigmoid + coalesced stores.
template<bool WS>
__global__ __launch_bounds__(64, 4) void k2_edges(
    const float* __restrict__ e1w, const float* __restrict__ e1b,
    const float* __restrict__ e2w, const float* __restrict__ e2b,
    float* __restrict__ out, const unsigned short* __restrict__ ebf)
{
  __shared__ float embi[64];
  __shared__ float ash[64];             // a_i[h] + e1_b[h]
  __shared__ float wds[64];             // e2w[h][1] - e2w[h][0]
  __shared__ __align__(16) float part[256][4];  // per-j partial logits
  const int t = threadIdx.x;            // lane 0..63
  const int blk = blockIdx.x;
  const int b = blk >> 10;              // 1024 blocks per batch
  const int rr = blk & 1023;
  const int i = rr >> 1;
  const int jh = rr & 1;                // j-half: [jh*256, jh*256+256)
  const float* __restrict__ Ef = out + EMB_OFF;

  embi[t] = Ef[((size_t)(b * NN) + i) * EMBD + t];
  wds[t]  = e2w[2 * t + 1] - e2w[2 * t];
  __syncthreads();

  {
    float acc = 0.f;
#pragma unroll 8
    for (int dd = 0; dd < EMBD; ++dd)
      acc = fmaf(embi[dd], e1w[dd * 64 + t], acc);
    ash[t] = acc + e1b[t];
  }
  __syncthreads();

  const int lg = t >> 4, ll = t & 15;

  f32x4 ci[4], wd4[4];
#pragma unroll
  for (int mt = 0; mt < 4; ++mt) {
    ci[mt]  = *reinterpret_cast<const f32x4*>(&ash[mt * 16 + lg * 4]);
    wd4[mt] = *reinterpret_cast<const f32x4*>(&wds[mt * 16 + lg * 4]);
  }

  // A fragments built directly in registers:
  // afr[mt][ks][q] = B'[d = ks*32+lg*8+q][h = mt*16+ll]
  bf16x8 afr[4][2];
#pragma unroll
  for (int ks = 0; ks < 2; ++ks) {
    float e8[8];
    *reinterpret_cast<float4*>(&e8[0]) =
        *reinterpret_cast<const float4*>(&embi[ks * 32 + lg * 8]);
    *reinterpret_cast<float4*>(&e8[4]) =
        *reinterpret_cast<const float4*>(&embi[ks * 32 + lg * 8 + 4]);
#pragma unroll
    for (int mt = 0; mt < 4; ++mt) {
      const int h = mt * 16 + ll;
      bf16x8 a;
#pragma unroll
      for (int q = 0; q < 8; ++q) {
        const int d = ks * 32 + lg * 8 + q;
        a[q] = bfs(fmaf(e8[q], e1w[(64 + d) * 64 + h], -e1w[d * 64 + h]));
      }
      afr[mt][ks] = a;
    }
  }

  auto loadB = [&](int j0, bf16x8& o0, bf16x8& o1) {
    if (WS) {
      const unsigned short* p =
          ebf + ((size_t)(b * NN) + j0 + ll) * EMBD + lg * 8;
      o0 = *reinterpret_cast<const bf16x8*>(p);
      o1 = *reinterpret_cast<const bf16x8*>(p + 32);
    } else {
      const float* ef = Ef + ((size_t)(b * NN) + j0 + ll) * EMBD + lg * 8;
      const float4 fa = *reinterpret_cast<const float4*>(ef);
      const float4 fb = *reinterpret_cast<const float4*>(ef + 4);
      const float4 fc = *reinterpret_cast<const float4*>(ef + 32);
      const float4 fd = *reinterpret_cast<const float4*>(ef + 36);
      o0 = pack8(fa, fb);
      o1 = pack8(fc, fd);
    }
  };

  auto process = [&](const bf16x8& b0, const bf16x8& b1, int nt) {
    f32x4 acc[4];
#pragma unroll
    for (int mt = 0; mt < 4; ++mt)
      acc[mt] = __builtin_amdgcn_mfma_f32_16x16x32_bf16(afr[mt][0], b0, ci[mt], 0, 0, 0);
#pragma unroll
    for (int mt = 0; mt < 4; ++mt)
      acc[mt] = __builtin_amdgcn_mfma_f32_16x16x32_bf16(afr[mt][1], b1, acc[mt], 0, 0, 0);

    float lp0 = 0.f, lp1 = 0.f, lp2 = 0.f, lp3 = 0.f;
#pragma unroll
    for (int mt = 0; mt < 4; ++mt) {
      lp0 = fmaf(fmaxf(acc[mt][0], 0.f), wd4[mt][0], lp0);
      lp1 = fmaf(fmaxf(acc[mt][1], 0.f), wd4[mt][1], lp1);
      lp2 = fmaf(fmaxf(acc[mt][2], 0.f), wd4[mt][2], lp2);
      lp3 = fmaf(fmaxf(acc[mt][3], 0.f), wd4[mt][3], lp3);
    }
    part[nt * 16 + ll][lg] = (lp0 + lp1) + (lp2 + lp3);
  };

  const int jbase = jh * 256;
  // depth-2 prefetch: two tile-pairs in rotation
  bf16x8 a0, a1, c0, c1;
  loadB(jbase, a0, a1);
  loadB(jbase + 16, c0, c1);

  for (int base = 0; base < 16; base += 2) {
    process(a0, a1, base);
    if (base + 2 < 16) loadB(jbase + (base + 2) * 16, a0, a1);
    process(c0, c1, base + 1);
    if (base + 3 < 16) loadB(jbase + (base + 3) * 16, c0, c1);
  }
  __syncthreads();

  // Deferred epilogue: each lane finishes 4 j's (sigmoid + coalesced stores)
  const float ldbias = e2b[1] - e2b[0];
  const size_t adj_base = ((size_t)(b * NN) + i) * NN + jbase;
  const size_t pred_base =
      (size_t)PRED_OFF + (size_t)b * PRED_PER_B + (size_t)i * (NN - 1) * 2;

#pragma unroll
  for (int e4 = 0; e4 < 4; ++e4) {
    const int jl = e4 * 64 + t;
    const f32x4 p4 = *reinterpret_cast<const f32x4*>(&part[jl][0]);
    const float x = (p4[0] + p4[1]) + (p4[2] + p4[3]) + ldbias;
    const float e = __builtin_amdgcn_exp2f(x * -1.44269504f);
    const float p1 = __builtin_amdgcn_rcpf(1.f + e);
    const float p0 = e * p1;

    const int j = jbase + jl;
    out[adj_base + jl] = p1;
    if (j != i) {
      const int jj = j - (j > i ? 1 : 0);
      *reinterpret_cast<float2*>(out + pred_base + (size_t)jj * 2) =
          make_float2(p0, p1);
    }
  }
}

extern "C" void kernel_launch(void* const* d_in, const int* in_sizes, int n_in,
                              void* d_out, int out_size, void* d_ws, size_t ws_size,
                              hipStream_t stream) {
  const float* nf   = (const float*)d_in[0];
  const float* fc1w = (const float*)d_in[1];
  const float* fc1b = (const float*)d_in[2];
  const float* fc2w = (const float*)d_in[3];
  const float* fc2b = (const float*)d_in[4];
  const float* e1w  = (const float*)d_in[5];
  const float* e1b  = (const float*)d_in[6];
  const float* e2w  = (const float*)d_in[7];
  const float* e2b  = (const float*)d_in[8];
  float* out = (float*)d_out;
  unsigned short* ebf = (unsigned short*)d_ws;
  const bool use_ws = ws_size >= (size_t)BSZ * NN * EMBD * sizeof(unsigned short);

  if (use_ws) {
    k1_embed<true><<<BSZ * NN / 4, 256, 0, stream>>>(nf, fc1w, fc1b, fc2w, fc2b, out, ebf);
    k2_edges<true><<<BSZ * NN * 2, 64, 0, stream>>>(e1w, e1b, e2w, e2b, out, ebf);
  } else {
    k1_embed<false><<<BSZ * NN / 4, 256, 0, stream>>>(nf, fc1w, fc1b, fc2w, fc2b, out, nullptr);
    k2_edges<false><<<BSZ * NN * 2, 64, 0, stream>>>(e1w, e1b, e2w, e2b, out, nullptr);
  }
}